// Round 2
// 1231.612 us; speedup vs baseline: 1.0221x; 1.0221x over previous
//
#include <hip/hip_runtime.h>

#define NND 4096
#define NED 4096
#define NNZK 32768
#define BB 64
#define CC 256
#define MM (NND * BB)

// batch-axis slicing of aggregation: 4 slices x 16 batches, 8KB per node-row slice
#define SLICES 4
#define SLBYTES 8192

typedef __attribute__((ext_vector_type(8))) __bf16 bf16x8;
typedef __attribute__((ext_vector_type(4))) float f32x4;

__device__ __forceinline__ float b2f(unsigned short h) {
  unsigned int v = ((unsigned int)h) << 16;
  return __builtin_bit_cast(float, v);
}
__device__ __forceinline__ unsigned short f2b(float f) {
  unsigned int v = __builtin_bit_cast(unsigned int, f);
  v = v + 0x7FFFu + ((v >> 16) & 1u);
  return (unsigned short)(v >> 16);
}
// accumulate packed pair of bf16 (low, high) into two fp32 accs
__device__ __forceinline__ void acc2(float& a0, float& a1, unsigned int v) {
  a0 += __builtin_bit_cast(float, v << 16);
  a1 += __builtin_bit_cast(float, v & 0xffff0000u);
}
__device__ __forceinline__ unsigned int pack2(float a0, float a1) {
  return (unsigned int)f2b(a0) | ((unsigned int)f2b(a1) << 16);
}

// ---- CSR build -------------------------------------------------------------
__global__ __launch_bounds__(256) void hist_k(const int* __restrict__ src,
                                              const int* __restrict__ dst,
                                              int* __restrict__ DdegI,
                                              int* __restrict__ BdegI) {
  int i = blockIdx.x * 256 + threadIdx.x;
  atomicAdd(&DdegI[src[i]], 1);
  atomicAdd(&BdegI[dst[i]], 1);
}

__global__ __launch_bounds__(256) void scan_k(const int* __restrict__ degB, int* __restrict__ offB,
                                              int* __restrict__ curB, float* __restrict__ invB,
                                              const int* __restrict__ degD, int* __restrict__ offD,
                                              int* __restrict__ curD, float* __restrict__ invD) {
  const int* deg; int* off; int* cur; float* inv;
  if (blockIdx.x == 0) { deg = degB; off = offB; cur = curB; inv = invB; }
  else                 { deg = degD; off = offD; cur = curD; inv = invD; }
  int t = threadIdx.x;
  int base = t * 16;
  int v[16]; int s = 0;
  #pragma unroll
  for (int i = 0; i < 16; ++i) { v[i] = deg[base + i]; s += v[i]; }
  __shared__ int sm[256];
  sm[t] = s;
  __syncthreads();
  for (int d = 1; d < 256; d <<= 1) {
    int x = (t >= d) ? sm[t - d] : 0;
    __syncthreads();
    sm[t] += x;
    __syncthreads();
  }
  int excl = sm[t] - s;
  #pragma unroll
  for (int i = 0; i < 16; ++i) {
    off[base + i] = excl;
    cur[base + i] = excl;
    int dv = v[i];
    inv[base + i] = (dv > 0) ? (1.0f / (float)dv) : 0.0f;
    excl += dv;
  }
  if (t == 255) off[4096] = excl;
}

__global__ __launch_bounds__(256) void fill_k(const int* __restrict__ src,
                                              const int* __restrict__ dst,
                                              int* __restrict__ curB, int* __restrict__ curD,
                                              int* __restrict__ listB, int* __restrict__ listD) {
  int i = blockIdx.x * 256 + threadIdx.x;
  int s = src[i], d = dst[i];
  int p = atomicAdd(&curB[d], 1);
  listB[p] = s;
  int q = atomicAdd(&curD[s], 1);
  listD[q] = d;
}

// ---- converts --------------------------------------------------------------
__global__ __launch_bounds__(256) void cvt_x_k(const float* __restrict__ x,
                                               unsigned short* __restrict__ xb) {
  int blk = blockIdx.x * 4 + (threadIdx.x >> 6);
  int b = blk >> 12, n = blk & 4095;
  int t = threadIdx.x & 63;
  float4 v = *(const float4*)(x + (size_t)blk * CC + t * 4);
  ushort4 o;
  o.x = f2b(v.x); o.y = f2b(v.y); o.z = f2b(v.z); o.w = f2b(v.w);
  *(ushort4*)(xb + (((size_t)n << 6) + b) * CC + t * 4) = o;
}

__global__ __launch_bounds__(256) void cvt_w_k(const float* __restrict__ W,
                                               unsigned short* __restrict__ Wt) {
  int k = blockIdx.x, n = threadIdx.x;
  Wt[n * CC + k] = f2b(W[k * CC + n]);
}

// ---- 128x128 bf16 MFMA GEMM: C[m][n] = sum_k A[m][k] * Bt[n][k] ------------
__global__ __launch_bounds__(256) void gemm128(const unsigned short* __restrict__ A,
                                               const unsigned short* __restrict__ Bt,
                                               unsigned short* __restrict__ C) {
  __shared__ __align__(16) unsigned short Al[128][40];  // +8 pad -> 2-way banks (free)
  __shared__ __align__(16) unsigned short Bl[128][40];
  int t = threadIdx.x;
  int w = t >> 6, l = t & 63;
  int wm = w >> 1, wn = w & 1;
  int m0 = blockIdx.x * 128, n0 = blockIdx.y * 128;
  int ml = l & 15, ko = (l >> 4) * 8;
  f32x4 acc[4][4] = {};
  int sr = t >> 2, sc = (t & 3) * 8;            // 64 rows x 64B per pass, x2
  const unsigned short* Ap = A  + (size_t)(m0 + sr) * CC + sc;
  const unsigned short* Bp = Bt + (size_t)(n0 + sr) * CC + sc;
  for (int kt = 0; kt < 8; ++kt) {
    uint4 a0v = *(const uint4*)(Ap + kt * 32);
    uint4 a1v = *(const uint4*)(Ap + (size_t)64 * CC + kt * 32);
    uint4 b0v = *(const uint4*)(Bp + kt * 32);
    uint4 b1v = *(const uint4*)(Bp + (size_t)64 * CC + kt * 32);
    __syncthreads();
    *(uint4*)&Al[sr][sc]      = a0v;
    *(uint4*)&Al[64 + sr][sc] = a1v;
    *(uint4*)&Bl[sr][sc]      = b0v;
    *(uint4*)&Bl[64 + sr][sc] = b1v;
    __syncthreads();
    bf16x8 af[4], bf[4];
    #pragma unroll
    for (int i = 0; i < 4; ++i) {
      af[i] = __builtin_bit_cast(bf16x8, *(const uint4*)&Al[wm * 64 + i * 16 + ml][ko]);
      bf[i] = __builtin_bit_cast(bf16x8, *(const uint4*)&Bl[wn * 64 + i * 16 + ml][ko]);
    }
    #pragma unroll
    for (int i = 0; i < 4; ++i)
      #pragma unroll
      for (int j = 0; j < 4; ++j)
        acc[i][j] = __builtin_amdgcn_mfma_f32_16x16x32_bf16(af[i], bf[j], acc[i][j], 0, 0, 0);
  }
  int q = l >> 4;
  #pragma unroll
  for (int i = 0; i < 4; ++i) {
    size_t rowb = (size_t)(m0 + wm * 64 + i * 16 + q * 4) * CC + n0 + wn * 64 + ml;
    #pragma unroll
    for (int j = 0; j < 4; ++j)
      #pragma unroll
      for (int r = 0; r < 4; ++r)
        C[rowb + (size_t)r * CC + j * 16] = f2b(acc[i][j][r]);
  }
}

// ---- aggregation: block per (slice, segment e) ------------------------------
// Slice-major dispatch phases the working set: during one slice-phase the
// active read+write footprint is ~33MB+33MB, which the 256MB L3 retains, so
// the deg~8x reuse of each node-row slice is served by L3 instead of DRAM.
// Per block: for each j in CSR list of e, read 8KB contiguous (16 batches x
// 256ch bf16), accumulate 16 fp32/thread. k-loop unrolled x2 for MLP.
__global__ __launch_bounds__(256) void agg4_k(const unsigned short* __restrict__ X,
                                              const int* __restrict__ off,
                                              const int* __restrict__ lst,
                                              const float* __restrict__ inv,
                                              const float* __restrict__ bias,
                                              unsigned short* __restrict__ Yb,
                                              float* __restrict__ Yf) {
  int e = blockIdx.x & 4095;
  int s = blockIdx.x >> 12;   // slice index, slice-major so slices phase in time
  int t = threadIdx.x;
  int beg = off[e], end = off[e + 1];
  float acc[16];
  #pragma unroll
  for (int i = 0; i < 16; ++i) acc[i] = 0.f;
  const char* Xb = (const char*)X + (size_t)s * SLBYTES + (size_t)t * 16;
  int k = beg;
  for (; k + 2 <= end; k += 2) {
    int j0 = lst[k], j1 = lst[k + 1];
    const char* r0 = Xb + (size_t)j0 * 32768;
    const char* r1 = Xb + (size_t)j1 * 32768;
    uint4 a0 = *(const uint4*)(r0);
    uint4 a1 = *(const uint4*)(r0 + 4096);
    uint4 b0 = *(const uint4*)(r1);
    uint4 b1 = *(const uint4*)(r1 + 4096);
    acc2(acc[0],  acc[1],  a0.x); acc2(acc[2],  acc[3],  a0.y);
    acc2(acc[4],  acc[5],  a0.z); acc2(acc[6],  acc[7],  a0.w);
    acc2(acc[8],  acc[9],  a1.x); acc2(acc[10], acc[11], a1.y);
    acc2(acc[12], acc[13], a1.z); acc2(acc[14], acc[15], a1.w);
    acc2(acc[0],  acc[1],  b0.x); acc2(acc[2],  acc[3],  b0.y);
    acc2(acc[4],  acc[5],  b0.z); acc2(acc[6],  acc[7],  b0.w);
    acc2(acc[8],  acc[9],  b1.x); acc2(acc[10], acc[11], b1.y);
    acc2(acc[12], acc[13], b1.z); acc2(acc[14], acc[15], b1.w);
  }
  if (k < end) {
    int j0 = lst[k];
    const char* r0 = Xb + (size_t)j0 * 32768;
    uint4 a0 = *(const uint4*)(r0);
    uint4 a1 = *(const uint4*)(r0 + 4096);
    acc2(acc[0],  acc[1],  a0.x); acc2(acc[2],  acc[3],  a0.y);
    acc2(acc[4],  acc[5],  a0.z); acc2(acc[6],  acc[7],  a0.w);
    acc2(acc[8],  acc[9],  a1.x); acc2(acc[10], acc[11], a1.y);
    acc2(acc[12], acc[13], a1.z); acc2(acc[14], acc[15], a1.w);
  }
  float sc = inv[e];
  float bv[8];
  if (bias) {
    float4 bb0 = *(const float4*)(bias + (t & 31) * 8);
    float4 bb1 = *(const float4*)(bias + (t & 31) * 8 + 4);
    bv[0] = bb0.x; bv[1] = bb0.y; bv[2] = bb0.z; bv[3] = bb0.w;
    bv[4] = bb1.x; bv[5] = bb1.y; bv[6] = bb1.z; bv[7] = bb1.w;
  } else {
    #pragma unroll
    for (int j2 = 0; j2 < 8; ++j2) bv[j2] = 0.f;
  }
  #pragma unroll
  for (int i = 0; i < 16; ++i) acc[i] = acc[i] * sc + bv[i & 7];
  if (Yf) {
    int c0 = (t & 31) * 8;
    #pragma unroll
    for (int i = 0; i < 2; ++i) {
      int b = s * 16 + (t >> 5) + i * 8;
      float* op = Yf + ((size_t)b * 4096 + e) * 256 + c0;
      float4 o0 = make_float4(acc[i * 8 + 0], acc[i * 8 + 1], acc[i * 8 + 2], acc[i * 8 + 3]);
      float4 o1 = make_float4(acc[i * 8 + 4], acc[i * 8 + 5], acc[i * 8 + 6], acc[i * 8 + 7]);
      *(float4*)op = o0;
      *(float4*)(op + 4) = o1;
    }
  } else {
    char* wp = (char*)Yb + (size_t)e * 32768 + (size_t)s * SLBYTES + (size_t)t * 16;
    #pragma unroll
    for (int i = 0; i < 2; ++i) {
      uint4 o;
      o.x = pack2(acc[i * 8 + 0], acc[i * 8 + 1]);
      o.y = pack2(acc[i * 8 + 2], acc[i * 8 + 3]);
      o.z = pack2(acc[i * 8 + 4], acc[i * 8 + 5]);
      o.w = pack2(acc[i * 8 + 6], acc[i * 8 + 7]);
      *(uint4*)(wp + i * 4096) = o;
    }
  }
}

extern "C" void kernel_launch(void* const* d_in, const int* in_sizes, int n_in,
                              void* d_out, int out_size, void* d_ws, size_t ws_size,
                              hipStream_t stream) {
  const float* x  = (const float*)d_in[0];
  const int*   he = (const int*)d_in[1];
  const float* W1 = (const float*)d_in[2];
  const float* b1 = (const float*)d_in[3];
  const float* W2 = (const float*)d_in[4];
  const float* b2 = (const float*)d_in[5];
  const int* src = he;
  const int* dst = he + NNZK;
  float* out = (float*)d_out;

  char* ws = (char*)d_ws;
  size_t o = 0;
  auto alloc = [&](size_t bytes) {
    char* p = ws + o;
    o += (bytes + 255) & ~(size_t)255;
    return p;
  };
  unsigned short* xb  = (unsigned short*)alloc((size_t)MM * CC * 2);
  unsigned short* xw  = (unsigned short*)alloc((size_t)MM * CC * 2);
  unsigned short* edg = (unsigned short*)alloc((size_t)MM * CC * 2);
  unsigned short* Wt1 = (unsigned short*)alloc((size_t)CC * CC * 2);
  unsigned short* Wt2 = (unsigned short*)alloc((size_t)CC * CC * 2);
  int* BdegI = (int*)alloc(NED * 4);
  int* DdegI = (int*)alloc(NND * 4);
  int* offB  = (int*)alloc((NED + 1) * 4);
  int* offD  = (int*)alloc((NND + 1) * 4);
  int* curB  = (int*)alloc(NED * 4);
  int* curD  = (int*)alloc(NND * 4);
  int* listB = (int*)alloc(NNZK * 4);
  int* listD = (int*)alloc(NNZK * 4);
  float* Binv = (float*)alloc(NED * 4);
  float* Dinv = (float*)alloc(NND * 4);

  hipMemsetAsync(BdegI, 0, NED * 4, stream);
  hipMemsetAsync(DdegI, 0, NND * 4, stream);

  hist_k<<<NNZK / 256, 256, 0, stream>>>(src, dst, DdegI, BdegI);
  scan_k<<<2, 256, 0, stream>>>(BdegI, offB, curB, Binv, DdegI, offD, curD, Dinv);
  fill_k<<<NNZK / 256, 256, 0, stream>>>(src, dst, curB, curD, listB, listD);

  cvt_x_k<<<(BB * NND) / 4, 256, 0, stream>>>(x, xb);
  cvt_w_k<<<CC, CC, 0, stream>>>(W1, Wt1);
  cvt_w_k<<<CC, CC, 0, stream>>>(W2, Wt2);

  dim3 gg(MM / 128, CC / 128);
  // layer 1
  gemm128<<<gg, 256, 0, stream>>>(xb, Wt1, xw);
  agg4_k<<<NED * SLICES, 256, 0, stream>>>(xw, offB, listB, Binv, nullptr, edg, nullptr);
  agg4_k<<<NND * SLICES, 256, 0, stream>>>(edg, offD, listD, Dinv, b1, xb, nullptr);
  // layer 2
  gemm128<<<gg, 256, 0, stream>>>(xb, Wt2, xw);
  agg4_k<<<NED * SLICES, 256, 0, stream>>>(xw, offB, listB, Binv, nullptr, edg, nullptr);
  agg4_k<<<NND * SLICES, 256, 0, stream>>>(edg, offD, listD, Dinv, b2, nullptr, out);
}